// Round 6
// baseline (913.266 us; speedup 1.0000x reference)
//
#include <hip/hip_runtime.h>
#include <hip/hip_fp16.h>
#include <math.h>

#define NN 100000
#define NE 1600000
#define NB ((NN + 255) >> 8)   // 391 buckets of 256 nodes
#define CHUNK 8192
#define CAP 8192

typedef __attribute__((ext_vector_type(4))) float floatx4;
typedef __attribute__((ext_vector_type(8))) short shortx8;

// ---------------- bucketed CSR build ----------------

__global__ __launch_bounds__(256)
void coarse_hist(const int* __restrict__ ei, int* __restrict__ bucket_cnt, int E) {
    __shared__ int h[512];
    int t = threadIdx.x;
    for (int i = t; i < 512; i += 256) h[i] = 0;
    __syncthreads();
    int base = blockIdx.x * CHUNK;
    int lim = min(base + CHUNK, E);
    for (int e = base + t; e < lim; e += 256) {
        int d = ei[E + e];
        atomicAdd(&h[d >> 8], 1);
    }
    __syncthreads();
    for (int i = t; i < 512; i += 256)
        if (h[i]) atomicAdd(&bucket_cnt[i], h[i]);
}

__global__ void scan_buckets(const int* __restrict__ bucket_cnt,
                             int* __restrict__ bucket_base,
                             int* __restrict__ bucket_fill) {
    __shared__ int sh[512];
    int t = threadIdx.x;  // 512 threads
    int v = (t < NB) ? bucket_cnt[t] : 0;
    sh[t] = v;
    __syncthreads();
    for (int off = 1; off < 512; off <<= 1) {
        int u = (t >= off) ? sh[t - off] : 0;
        __syncthreads();
        sh[t] += u;
        __syncthreads();
    }
    int ex = (t == 0) ? 0 : sh[t - 1];
    if (t <= NB) bucket_base[t] = ex;
    if (t < NB) bucket_fill[t] = ex;
}

__global__ __launch_bounds__(256)
void coarse_scatter(const int* __restrict__ ei, int* __restrict__ bucket_fill,
                    unsigned long long* __restrict__ pairs, int E) {
    __shared__ int h[512];
    __shared__ int base[512];
    int t = threadIdx.x;
    for (int i = t; i < 512; i += 256) h[i] = 0;
    __syncthreads();
    int cbase = blockIdx.x * CHUNK;
    int lim = min(cbase + CHUNK, E);
    for (int e = cbase + t; e < lim; e += 256) {
        int d = ei[E + e];
        atomicAdd(&h[d >> 8], 1);
    }
    __syncthreads();
    for (int i = t; i < 512; i += 256)
        base[i] = h[i] ? atomicAdd(&bucket_fill[i], h[i]) : 0;
    __syncthreads();
    for (int i = t; i < 512; i += 256) h[i] = 0;
    __syncthreads();
    for (int e = cbase + t; e < lim; e += 256) {
        int s = ei[e];
        int d = ei[E + e];
        int b = d >> 8;
        int r = atomicAdd(&h[b], 1);
        pairs[base[b] + r] =
            ((unsigned long long)(unsigned)d << 32) | (unsigned)s;
    }
}

__global__ __launch_bounds__(256)
void fine_csr(const unsigned long long* __restrict__ pairs,
              const int* __restrict__ bucket_base,
              int* __restrict__ rowptr, int* __restrict__ colid,
              float* __restrict__ dinv, int n) {
    __shared__ int hist[256];
    __shared__ int offs[256];
    __shared__ int rank[256];
    __shared__ int lbuf[CAP];
    int b = blockIdx.x, t = threadIdx.x;
    int beg = bucket_base[b], end = bucket_base[b + 1];
    int cnt = end - beg;
    hist[t] = 0; rank[t] = 0;
    __syncthreads();
    for (int i = t; i < cnt; i += 256) {
        int d = (int)(pairs[beg + i] >> 32);
        atomicAdd(&hist[d & 255], 1);
    }
    __syncthreads();
    int v = hist[t];
    offs[t] = v;
    __syncthreads();
    for (int off = 1; off < 256; off <<= 1) {
        int u = (t >= off) ? offs[t - off] : 0;
        __syncthreads();
        offs[t] += u;
        __syncthreads();
    }
    int ex = (t == 0) ? 0 : offs[t - 1];
    int node = (b << 8) + t;
    if (node < n) {
        rowptr[node] = beg + ex;
        dinv[node] = rsqrtf((float)v + 1.0f);
    } else if (node == n) {
        rowptr[n] = beg + ex;
    }
    __syncthreads();
    offs[t] = ex;
    __syncthreads();
    for (int i = t; i < cnt; i += 256) {
        unsigned long long p = pairs[beg + i];
        int d = (int)(p >> 32) & 255;
        int s = (int)(p & 0xffffffffu);
        int r = atomicAdd(&rank[d], 1);
        lbuf[offs[d] + r] = s;
    }
    __syncthreads();
    for (int i = t; i < cnt; i += 256) colid[beg + i] = lbuf[i];
}

// ---------------- concat helpers ----------------

__global__ void concat_kernel(const float4* __restrict__ f, const float4* __restrict__ c,
                              float4* __restrict__ A, int n) {
    int i = blockIdx.x * 256 + threadIdx.x;
    int total = n * 40;
    if (i < total) {
        int row = i / 40, j = i % 40;
        A[i] = (j < 32) ? f[row * 32 + j] : c[row * 8 + (j - 32)];
    }
}

__global__ void condcopy_kernel(const float4* __restrict__ c, float4* __restrict__ A, int n) {
    int i = blockIdx.x * 256 + threadIdx.x;
    if (i < n * 8) {
        int row = i / 8, j = i % 8;
        A[row * 24 + 16 + j] = c[row * 8 + j];
    }
}

// ---------------- weight prep: W[K][OUT] fp32 -> W^T hi/lo bf16 [OUT][K] ----------------

__global__ void wsplit_kernel(const float* __restrict__ W,
                              unsigned short* __restrict__ hi,
                              unsigned short* __restrict__ lo,
                              int K, int OUT) {
    int i = blockIdx.x * 256 + threadIdx.x;
    if (i < K * OUT) {
        int k = i / OUT, o = i % OUT;
        float w = W[i];
        unsigned u = __float_as_uint(w);
        float r = w - __uint_as_float(u & 0xFFFF0000u);
        hi[o * K + k] = (unsigned short)(u >> 16);
        lo[o * K + k] = (unsigned short)(__float_as_uint(r) >> 16);
    }
}

// ---------------- MFMA GEMM: Y16[n][OUT] = fp16( (X[n][K] @ W) * dinv[row] ) ----------------
// bf16x3 split: full fp32-grade precision. One wave per 16-row tile, no LDS.
// Layouts (guide-verified): A[m=lane&15][k=quad*8+j]; B[k][n=lane&15];
// D: col=lane&15, row=quad*4+reg.

__device__ __forceinline__ void split8(const float* v, shortx8& hi, shortx8& lo) {
#pragma unroll
    for (int i = 0; i < 8; i++) {
        unsigned u = __float_as_uint(v[i]);
        float r = v[i] - __uint_as_float(u & 0xFFFF0000u);
        hi[i] = (short)(u >> 16);
        lo[i] = (short)(__float_as_uint(r) >> 16);
    }
}

template <int OUT, int K>
__global__ __launch_bounds__(256)
void gemm_mfma(const float* __restrict__ X,
               const unsigned short* __restrict__ WThi,
               const unsigned short* __restrict__ WTlo,
               const float* __restrict__ dinv,
               __half* __restrict__ Y, int ntiles) {
    constexpr int NT = OUT / 16;
    int wave = threadIdx.x >> 6;
    int lane = threadIdx.x & 63;
    int tile = blockIdx.x * 4 + wave;
    if (tile >= ntiles) return;
    int m = lane & 15;
    int q = lane >> 4;
    const float* ap = X + (size_t)(tile * 16 + m) * K + q * 8;

    floatx4 acc[NT];
#pragma unroll
    for (int nt = 0; nt < NT; nt++) acc[nt] = (floatx4){0.f, 0.f, 0.f, 0.f};

#pragma unroll
    for (int kt = 0; kt < K; kt += 32) {
        float av[8];
        *(float4*)&av[0] = *(const float4*)(ap + kt);
        *(float4*)&av[4] = *(const float4*)(ap + kt + 4);
        shortx8 ahi, alo;
        split8(av, ahi, alo);
#pragma unroll
        for (int nt = 0; nt < NT; nt++) {
            const unsigned short* bp = WThi + (size_t)(nt * 16 + m) * K + kt + q * 8;
            const unsigned short* lp = WTlo + (size_t)(nt * 16 + m) * K + kt + q * 8;
            shortx8 bhi = *(const shortx8*)bp;
            shortx8 blo = *(const shortx8*)lp;
            acc[nt] = __builtin_amdgcn_mfma_f32_16x16x32_bf16(ahi, bhi, acc[nt], 0, 0, 0);
            acc[nt] = __builtin_amdgcn_mfma_f32_16x16x32_bf16(ahi, blo, acc[nt], 0, 0, 0);
            acc[nt] = __builtin_amdgcn_mfma_f32_16x16x32_bf16(alo, bhi, acc[nt], 0, 0, 0);
        }
    }

    float di[4];
#pragma unroll
    for (int r = 0; r < 4; r++) di[r] = dinv[tile * 16 + q * 4 + r];
#pragma unroll
    for (int nt = 0; nt < NT; nt++) {
#pragma unroll
        for (int r = 0; r < 4; r++) {
            int orow = tile * 16 + q * 4 + r;
            Y[(size_t)orow * OUT + nt * 16 + m] = __float2half_rn(acc[nt][r] * di[r]);
        }
    }
}

// ---------------- propagation (fp16 gather, fp32 accumulate) ----------------

template <int OUT, bool TANH>
__global__ __launch_bounds__(256)
void prop_kernel(const __half* __restrict__ hs, const float* __restrict__ dinv,
                 const int* __restrict__ rowptr, const int* __restrict__ colid,
                 const float* __restrict__ bias,
                 float* __restrict__ out, int ldo, int n) {
    int wave = threadIdx.x >> 6;
    int lane = threadIdx.x & 63;
    int node = blockIdx.x * 4 + wave;
    if (node >= n) return;
    int beg = rowptr[node], end = rowptr[node + 1];

    if constexpr (OUT == 128) {
        const __half2* base = (const __half2*)hs;
        float2 self = __half22float2(base[(size_t)node * 64 + lane]);
        float accx = self.x, accy = self.y;
        float accx2 = 0.f, accy2 = 0.f;
        int e = beg;
        for (; e + 8 <= end; e += 8) {
            int s[8];
#pragma unroll
            for (int j = 0; j < 8; j++) s[j] = colid[e + j];
            __half2 v[8];
#pragma unroll
            for (int j = 0; j < 8; j++) v[j] = base[(size_t)s[j] * 64 + lane];
#pragma unroll
            for (int j = 0; j < 8; j += 2) {
                float2 f0 = __half22float2(v[j]);
                float2 f1 = __half22float2(v[j + 1]);
                accx += f0.x; accy += f0.y;
                accx2 += f1.x; accy2 += f1.y;
            }
        }
        if (e + 4 <= end) {
            int s[4];
#pragma unroll
            for (int j = 0; j < 4; j++) s[j] = colid[e + j];
            __half2 v[4];
#pragma unroll
            for (int j = 0; j < 4; j++) v[j] = base[(size_t)s[j] * 64 + lane];
            float2 f0 = __half22float2(v[0]), f1 = __half22float2(v[1]);
            float2 f2 = __half22float2(v[2]), f3 = __half22float2(v[3]);
            accx += f0.x + f2.x; accy += f0.y + f2.y;
            accx2 += f1.x + f3.x; accy2 += f1.y + f3.y;
            e += 4;
        }
        for (; e < end; e++) {
            float2 f = __half22float2(base[(size_t)colid[e] * 64 + lane]);
            accx += f.x; accy += f.y;
        }
        accx += accx2; accy += accy2;
        float di = dinv[node];
        float ox = di * accx + bias[2 * lane];
        float oy = di * accy + bias[2 * lane + 1];
        if (TANH) { ox = tanhf(ox); oy = tanhf(oy); }
        *(float2*)(out + (size_t)node * ldo + 2 * lane) = make_float2(ox, oy);
    } else {
        float acc = __half2float(hs[(size_t)node * 64 + lane]);
        float acc2 = 0.f;
        int e = beg;
        for (; e + 8 <= end; e += 8) {
            int s[8];
#pragma unroll
            for (int j = 0; j < 8; j++) s[j] = colid[e + j];
            __half v[8];
#pragma unroll
            for (int j = 0; j < 8; j++) v[j] = hs[(size_t)s[j] * 64 + lane];
#pragma unroll
            for (int j = 0; j < 8; j += 2) {
                acc += __half2float(v[j]);
                acc2 += __half2float(v[j + 1]);
            }
        }
        if (e + 4 <= end) {
            int s[4];
#pragma unroll
            for (int j = 0; j < 4; j++) s[j] = colid[e + j];
            __half v[4];
#pragma unroll
            for (int j = 0; j < 4; j++) v[j] = hs[(size_t)s[j] * 64 + lane];
            acc += __half2float(v[0]) + __half2float(v[2]);
            acc2 += __half2float(v[1]) + __half2float(v[3]);
            e += 4;
        }
        for (; e < end; e++) acc += __half2float(hs[(size_t)colid[e] * 64 + lane]);
        acc += acc2;
        float v = dinv[node] * acc + bias[lane];
        if (TANH) v = tanhf(v);
        out[(size_t)node * ldo + lane] = v;
    }
}

// ---------------- launch ----------------

extern "C" void kernel_launch(void* const* d_in, const int* in_sizes, int n_in,
                              void* d_out, int out_size, void* d_ws, size_t ws_size,
                              hipStream_t stream) {
    const int n = NN, E = NE;
    const float* feature   = (const float*)d_in[0];
    const float* condition = (const float*)d_in[1];
    const int*   ei        = (const int*)d_in[2];
    const float* W_e1 = (const float*)d_in[3];  const float* b_e1 = (const float*)d_in[4];
    const float* W_e2 = (const float*)d_in[5];  const float* b_e2 = (const float*)d_in[6];
    const float* W_e3 = (const float*)d_in[7];  const float* b_e3 = (const float*)d_in[8];
    const float* W_d1 = (const float*)d_in[9];  const float* b_d1 = (const float*)d_in[10];
    const float* W_d2 = (const float*)d_in[11]; const float* b_d2 = (const float*)d_in[12];
    const float* W_d3 = (const float*)d_in[13]; const float* b_d3 = (const float*)d_in[14];
    float* out = (float*)d_out;

    float*  A    = (float*)d_ws;                    // n*160 floats
    __half* H16  = (__half*)(A + (size_t)n * 160);  // n*128 halves
    float*  dinv = (float*)(H16 + (size_t)n * 128); // n
    int* rowptr  = (int*)(dinv + n);                // n+1
    int* colid   = rowptr + n + 1;                  // E
    uintptr_t pp = (uintptr_t)(colid + E);
    pp = (pp + 15) & ~(uintptr_t)15;
    unsigned long long* pairs = (unsigned long long*)pp;  // E
    int* bucket_cnt  = (int*)(pairs + E);           // 512
    int* bucket_base = bucket_cnt + 512;            // 512
    int* bucket_fill = bucket_base + 512;           // 512
    uintptr_t wp = (uintptr_t)(bucket_fill + 512);
    wp = (wp + 15) & ~(uintptr_t)15;
    unsigned short* wt = (unsigned short*)wp;
    // per-layer W^T hi/lo (all 16B-aligned since sizes are multiples of 8 elems)
    unsigned short* e1h = wt;            unsigned short* e1l = e1h + 128 * 160;
    unsigned short* e2h = e1l + 128*160; unsigned short* e2l = e2h + 128 * 128;
    unsigned short* e3h = e2l + 128*128; unsigned short* e3l = e3h + 64 * 128;
    unsigned short* d1h = e3l + 64*128;  unsigned short* d1l = d1h + 128 * 96;
    unsigned short* d2h = d1l + 128*96;  unsigned short* d2l = d2h + 128 * 128;
    unsigned short* d3h = d2l + 128*128; unsigned short* d3l = d3h + 128 * 128;

    hipMemsetAsync(bucket_cnt, 0, 512 * sizeof(int), stream);

    int nbc = (E + CHUNK - 1) / CHUNK;
    coarse_hist<<<nbc, 256, 0, stream>>>(ei, bucket_cnt, E);
    scan_buckets<<<1, 512, 0, stream>>>(bucket_cnt, bucket_base, bucket_fill);
    coarse_scatter<<<nbc, 256, 0, stream>>>(ei, bucket_fill, pairs, E);
    fine_csr<<<NB, 256, 0, stream>>>(pairs, bucket_base, rowptr, colid, dinv, n);

    wsplit_kernel<<<(160*128 + 255)/256, 256, 0, stream>>>(W_e1, e1h, e1l, 160, 128);
    wsplit_kernel<<<(128*128 + 255)/256, 256, 0, stream>>>(W_e2, e2h, e2l, 128, 128);
    wsplit_kernel<<<(128*64  + 255)/256, 256, 0, stream>>>(W_e3, e3h, e3l, 128, 64);
    wsplit_kernel<<<(96*128  + 255)/256, 256, 0, stream>>>(W_d1, d1h, d1l, 96, 128);
    wsplit_kernel<<<(128*128 + 255)/256, 256, 0, stream>>>(W_d2, d2h, d2l, 128, 128);
    wsplit_kernel<<<(128*128 + 255)/256, 256, 0, stream>>>(W_d3, d3h, d3l, 128, 128);

    concat_kernel<<<(n * 40 + 255) / 256, 256, 0, stream>>>(
        (const float4*)feature, (const float4*)condition, (float4*)A, n);

    const int ntiles = n / 16;          // 6250 exactly
    const int gb = (ntiles + 3) / 4;    // 4 waves per block
    int pb = (n + 3) / 4;

    // encoder
    gemm_mfma<128, 160><<<gb, 256, 0, stream>>>(A, e1h, e1l, dinv, H16, ntiles);
    prop_kernel<128, true><<<pb, 256, 0, stream>>>(H16, dinv, rowptr, colid, b_e1, A, 128, n);
    gemm_mfma<128, 128><<<gb, 256, 0, stream>>>(A, e2h, e2l, dinv, H16, ntiles);
    prop_kernel<128, true><<<pb, 256, 0, stream>>>(H16, dinv, rowptr, colid, b_e2, A, 128, n);
    gemm_mfma<64, 128><<<gb, 256, 0, stream>>>(A, e3h, e3l, dinv, H16, ntiles);
    prop_kernel<64, false><<<pb, 256, 0, stream>>>(H16, dinv, rowptr, colid, b_e3, A, 96, n);
    condcopy_kernel<<<(n * 8 + 255) / 256, 256, 0, stream>>>(
        (const float4*)condition, (float4*)A, n);

    // decoder
    gemm_mfma<128, 96><<<gb, 256, 0, stream>>>(A, d1h, d1l, dinv, H16, ntiles);
    prop_kernel<128, true><<<pb, 256, 0, stream>>>(H16, dinv, rowptr, colid, b_d1, A, 128, n);
    gemm_mfma<128, 128><<<gb, 256, 0, stream>>>(A, d2h, d2l, dinv, H16, ntiles);
    prop_kernel<128, true><<<pb, 256, 0, stream>>>(H16, dinv, rowptr, colid, b_d2, A, 128, n);
    gemm_mfma<128, 128><<<gb, 256, 0, stream>>>(A, d3h, d3l, dinv, H16, ntiles);
    prop_kernel<128, false><<<pb, 256, 0, stream>>>(H16, dinv, rowptr, colid, b_d3, out, 128, n);
}

// Round 7
// 729.565 us; speedup vs baseline: 1.2518x; 1.2518x over previous
//
#include <hip/hip_runtime.h>
#include <hip/hip_fp16.h>
#include <math.h>

#define NN 100000
#define NE 1600000
#define NB ((NN + 255) >> 8)   // 391 buckets of 256 nodes
#define CHUNK 8192
#define CAP 8192

typedef __attribute__((ext_vector_type(4))) float floatx4;
typedef __attribute__((ext_vector_type(8))) short shortx8;

// ---------------- bucketed CSR build ----------------

__global__ __launch_bounds__(256)
void coarse_hist(const int* __restrict__ ei, int* __restrict__ bucket_cnt, int E) {
    __shared__ int h[512];
    int t = threadIdx.x;
    for (int i = t; i < 512; i += 256) h[i] = 0;
    __syncthreads();
    int base = blockIdx.x * CHUNK;
    int lim = min(base + CHUNK, E);
    for (int e = base + t; e < lim; e += 256) {
        int d = ei[E + e];
        atomicAdd(&h[d >> 8], 1);
    }
    __syncthreads();
    for (int i = t; i < 512; i += 256)
        if (h[i]) atomicAdd(&bucket_cnt[i], h[i]);
}

__global__ void scan_buckets(const int* __restrict__ bucket_cnt,
                             int* __restrict__ bucket_base,
                             int* __restrict__ bucket_fill) {
    __shared__ int sh[512];
    int t = threadIdx.x;  // 512 threads
    int v = (t < NB) ? bucket_cnt[t] : 0;
    sh[t] = v;
    __syncthreads();
    for (int off = 1; off < 512; off <<= 1) {
        int u = (t >= off) ? sh[t - off] : 0;
        __syncthreads();
        sh[t] += u;
        __syncthreads();
    }
    int ex = (t == 0) ? 0 : sh[t - 1];
    if (t <= NB) bucket_base[t] = ex;
    if (t < NB) bucket_fill[t] = ex;
}

__global__ __launch_bounds__(256)
void coarse_scatter(const int* __restrict__ ei, int* __restrict__ bucket_fill,
                    unsigned long long* __restrict__ pairs, int E) {
    __shared__ int h[512];
    __shared__ int base[512];
    int t = threadIdx.x;
    for (int i = t; i < 512; i += 256) h[i] = 0;
    __syncthreads();
    int cbase = blockIdx.x * CHUNK;
    int lim = min(cbase + CHUNK, E);
    for (int e = cbase + t; e < lim; e += 256) {
        int d = ei[E + e];
        atomicAdd(&h[d >> 8], 1);
    }
    __syncthreads();
    for (int i = t; i < 512; i += 256)
        base[i] = h[i] ? atomicAdd(&bucket_fill[i], h[i]) : 0;
    __syncthreads();
    for (int i = t; i < 512; i += 256) h[i] = 0;
    __syncthreads();
    for (int e = cbase + t; e < lim; e += 256) {
        int s = ei[e];
        int d = ei[E + e];
        int b = d >> 8;
        int r = atomicAdd(&h[b], 1);
        pairs[base[b] + r] =
            ((unsigned long long)(unsigned)d << 32) | (unsigned)s;
    }
}

__global__ __launch_bounds__(256)
void fine_csr(const unsigned long long* __restrict__ pairs,
              const int* __restrict__ bucket_base,
              int* __restrict__ rowptr, int* __restrict__ colid,
              float* __restrict__ dinv, int n) {
    __shared__ int hist[256];
    __shared__ int offs[256];
    __shared__ int rank[256];
    __shared__ int lbuf[CAP];
    int b = blockIdx.x, t = threadIdx.x;
    int beg = bucket_base[b], end = bucket_base[b + 1];
    int cnt = end - beg;
    hist[t] = 0; rank[t] = 0;
    __syncthreads();
    for (int i = t; i < cnt; i += 256) {
        int d = (int)(pairs[beg + i] >> 32);
        atomicAdd(&hist[d & 255], 1);
    }
    __syncthreads();
    int v = hist[t];
    offs[t] = v;
    __syncthreads();
    for (int off = 1; off < 256; off <<= 1) {
        int u = (t >= off) ? offs[t - off] : 0;
        __syncthreads();
        offs[t] += u;
        __syncthreads();
    }
    int ex = (t == 0) ? 0 : offs[t - 1];
    int node = (b << 8) + t;
    if (node < n) {
        rowptr[node] = beg + ex;
        dinv[node] = rsqrtf((float)v + 1.0f);
    } else if (node == n) {
        rowptr[n] = beg + ex;
    }
    __syncthreads();
    offs[t] = ex;
    __syncthreads();
    for (int i = t; i < cnt; i += 256) {
        unsigned long long p = pairs[beg + i];
        int d = (int)(p >> 32) & 255;
        int s = (int)(p & 0xffffffffu);
        int r = atomicAdd(&rank[d], 1);
        lbuf[offs[d] + r] = s;
    }
    __syncthreads();
    for (int i = t; i < cnt; i += 256) colid[beg + i] = lbuf[i];
}

// ---------------- concat helpers ----------------

__global__ void concat_kernel(const float4* __restrict__ f, const float4* __restrict__ c,
                              float4* __restrict__ A, int n) {
    int i = blockIdx.x * 256 + threadIdx.x;
    int total = n * 40;
    if (i < total) {
        int row = i / 40, j = i % 40;
        A[i] = (j < 32) ? f[row * 32 + j] : c[row * 8 + (j - 32)];
    }
}

__global__ void condcopy_kernel(const float4* __restrict__ c, float4* __restrict__ A, int n) {
    int i = blockIdx.x * 256 + threadIdx.x;
    if (i < n * 8) {
        int row = i / 8, j = i % 8;
        A[row * 24 + 16 + j] = c[row * 8 + j];
    }
}

// ---------------- weight prep: W[K][OUT] fp32 -> swizzled bf16 hi/lo fragments ----------------
// layout: [ktc][nt][h(hi=0,lo=1)][lane(=q*16+m)][j], 8 halfs per (.,lane)
// so a wave's ds_read_b128 at (ktc,nt,h) is lane-contiguous (conflict-free).

__global__ void wsplit_kernel(const float* __restrict__ W,
                              unsigned short* __restrict__ Wsw,
                              int K, int OUT) {
    int i = blockIdx.x * 256 + threadIdx.x;
    if (i < K * OUT) {
        int k = i / OUT, o = i % OUT;
        float w = W[i];
        unsigned u = __float_as_uint(w);
        float r = w - __uint_as_float(u & 0xFFFF0000u);
        int NT = OUT >> 4;
        int ktc = k >> 5, q = (k >> 3) & 3, j = k & 7;
        int nt = o >> 4, m = o & 15;
        int lane = (q << 4) | m;
        size_t base = ((((size_t)(ktc * NT + nt) * 2) * 64 + lane) << 3) + j;
        Wsw[base] = (unsigned short)(u >> 16);
        Wsw[base + 512] = (unsigned short)(__float_as_uint(r) >> 16);  // h=1: +64*8
    }
}

// ---------------- MFMA GEMM: Y16[n][OUT] = fp16( (X[n][K] @ W) * dinv[row] ) ----------------
// bf16x3 split, W fragments staged in LDS (pre-swizzled), 8 waves/block x 16 rows.

__device__ __forceinline__ void split8(const float* v, shortx8& hi, shortx8& lo) {
#pragma unroll
    for (int i = 0; i < 8; i++) {
        unsigned u = __float_as_uint(v[i]);
        float r = v[i] - __uint_as_float(u & 0xFFFF0000u);
        hi[i] = (short)(u >> 16);
        lo[i] = (short)(__float_as_uint(r) >> 16);
    }
}

template <int OUT, int K>
__global__ __launch_bounds__(512)
void gemm_mfma(const float* __restrict__ X,
               const unsigned short* __restrict__ Wsw,
               const float* __restrict__ dinv,
               __half* __restrict__ Y, int ntiles) {
    constexpr int NT = OUT / 16;
    constexpr int NKTC = K / 32;
    constexpr int PERC = OUT * 128;  // bytes per ktc chunk (NT*2*64*16)
    constexpr int CSZ = (65536 / PERC < NKTC) ? (65536 / PERC) : NKTC;
    __shared__ __align__(16) unsigned short lds[CSZ * PERC / 2];

    const int t = threadIdx.x;
    const int wave = t >> 6, lane = t & 63;
    const int m = lane & 15, q = lane >> 4;
    const int tile = blockIdx.x * 8 + wave;
    const bool act = tile < ntiles;
    const int row = act ? tile * 16 + m : 0;
    const float* ap = X + (size_t)row * K + q * 8;

    floatx4 acc[NT];
#pragma unroll
    for (int nt = 0; nt < NT; nt++) acc[nt] = (floatx4){0.f, 0.f, 0.f, 0.f};

#pragma unroll
    for (int c0 = 0; c0 < NKTC; c0 += CSZ) {
        const int cl = (NKTC - c0 < CSZ) ? (NKTC - c0) : CSZ;
        if (c0 != 0) __syncthreads();
        {
            const float4* gs = (const float4*)Wsw + (size_t)c0 * (PERC / 16);
            float4* ld = (float4*)lds;
            int tot = cl * (PERC / 16);
            for (int i = t; i < tot; i += 512) ld[i] = gs[i];
        }
        __syncthreads();
        if (act) {
#pragma unroll
            for (int ktc = 0; ktc < cl; ktc++) {
                int kg = (c0 + ktc) * 32;
                float av[8];
                *(float4*)&av[0] = *(const float4*)(ap + kg);
                *(float4*)&av[4] = *(const float4*)(ap + kg + 4);
                shortx8 ahi, alo;
                split8(av, ahi, alo);
#pragma unroll
                for (int nt = 0; nt < NT; nt++) {
                    const unsigned short* fb =
                        lds + ((((ktc * NT + nt) * 2) * 64 + lane) << 3);
                    shortx8 bhi = *(const shortx8*)fb;
                    shortx8 blo = *(const shortx8*)(fb + 512);
                    acc[nt] = __builtin_amdgcn_mfma_f32_16x16x32_bf16(ahi, bhi, acc[nt], 0, 0, 0);
                    acc[nt] = __builtin_amdgcn_mfma_f32_16x16x32_bf16(ahi, blo, acc[nt], 0, 0, 0);
                    acc[nt] = __builtin_amdgcn_mfma_f32_16x16x32_bf16(alo, bhi, acc[nt], 0, 0, 0);
                }
            }
        }
    }

    if (act) {
        float di[4];
#pragma unroll
        for (int r = 0; r < 4; r++) di[r] = dinv[tile * 16 + q * 4 + r];
#pragma unroll
        for (int nt = 0; nt < NT; nt++) {
#pragma unroll
            for (int r = 0; r < 4; r++) {
                int orow = tile * 16 + q * 4 + r;
                Y[(size_t)orow * OUT + nt * 16 + m] = __float2half_rn(acc[nt][r] * di[r]);
            }
        }
    }
}

// ---------------- propagation (fp16 gather, fp32 accumulate) ----------------

template <int OUT, bool TANH>
__global__ __launch_bounds__(256)
void prop_kernel(const __half* __restrict__ hs, const float* __restrict__ dinv,
                 const int* __restrict__ rowptr, const int* __restrict__ colid,
                 const float* __restrict__ bias,
                 float* __restrict__ out, int ldo, int n) {
    int wave = threadIdx.x >> 6;
    int lane = threadIdx.x & 63;
    int node = blockIdx.x * 4 + wave;
    if (node >= n) return;
    int beg = rowptr[node], end = rowptr[node + 1];

    if constexpr (OUT == 128) {
        const __half2* base = (const __half2*)hs;
        float2 self = __half22float2(base[(size_t)node * 64 + lane]);
        float accx = self.x, accy = self.y;
        float accx2 = 0.f, accy2 = 0.f;
        int e = beg;
        for (; e + 8 <= end; e += 8) {
            int s[8];
#pragma unroll
            for (int j = 0; j < 8; j++) s[j] = colid[e + j];
            __half2 v[8];
#pragma unroll
            for (int j = 0; j < 8; j++) v[j] = base[(size_t)s[j] * 64 + lane];
#pragma unroll
            for (int j = 0; j < 8; j += 2) {
                float2 f0 = __half22float2(v[j]);
                float2 f1 = __half22float2(v[j + 1]);
                accx += f0.x; accy += f0.y;
                accx2 += f1.x; accy2 += f1.y;
            }
        }
        if (e + 4 <= end) {
            int s[4];
#pragma unroll
            for (int j = 0; j < 4; j++) s[j] = colid[e + j];
            __half2 v[4];
#pragma unroll
            for (int j = 0; j < 4; j++) v[j] = base[(size_t)s[j] * 64 + lane];
            float2 f0 = __half22float2(v[0]), f1 = __half22float2(v[1]);
            float2 f2 = __half22float2(v[2]), f3 = __half22float2(v[3]);
            accx += f0.x + f2.x; accy += f0.y + f2.y;
            accx2 += f1.x + f3.x; accy2 += f1.y + f3.y;
            e += 4;
        }
        for (; e < end; e++) {
            float2 f = __half22float2(base[(size_t)colid[e] * 64 + lane]);
            accx += f.x; accy += f.y;
        }
        accx += accx2; accy += accy2;
        float di = dinv[node];
        float ox = di * accx + bias[2 * lane];
        float oy = di * accy + bias[2 * lane + 1];
        if (TANH) { ox = tanhf(ox); oy = tanhf(oy); }
        *(float2*)(out + (size_t)node * ldo + 2 * lane) = make_float2(ox, oy);
    } else {
        float acc = __half2float(hs[(size_t)node * 64 + lane]);
        float acc2 = 0.f;
        int e = beg;
        for (; e + 8 <= end; e += 8) {
            int s[8];
#pragma unroll
            for (int j = 0; j < 8; j++) s[j] = colid[e + j];
            __half v[8];
#pragma unroll
            for (int j = 0; j < 8; j++) v[j] = hs[(size_t)s[j] * 64 + lane];
#pragma unroll
            for (int j = 0; j < 8; j += 2) {
                acc += __half2float(v[j]);
                acc2 += __half2float(v[j + 1]);
            }
        }
        if (e + 4 <= end) {
            int s[4];
#pragma unroll
            for (int j = 0; j < 4; j++) s[j] = colid[e + j];
            __half v[4];
#pragma unroll
            for (int j = 0; j < 4; j++) v[j] = hs[(size_t)s[j] * 64 + lane];
            acc += __half2float(v[0]) + __half2float(v[2]);
            acc2 += __half2float(v[1]) + __half2float(v[3]);
            e += 4;
        }
        for (; e < end; e++) acc += __half2float(hs[(size_t)colid[e] * 64 + lane]);
        acc += acc2;
        float v = dinv[node] * acc + bias[lane];
        if (TANH) v = tanhf(v);
        out[(size_t)node * ldo + lane] = v;
    }
}

// ---------------- launch ----------------

extern "C" void kernel_launch(void* const* d_in, const int* in_sizes, int n_in,
                              void* d_out, int out_size, void* d_ws, size_t ws_size,
                              hipStream_t stream) {
    const int n = NN, E = NE;
    const float* feature   = (const float*)d_in[0];
    const float* condition = (const float*)d_in[1];
    const int*   ei        = (const int*)d_in[2];
    const float* W_e1 = (const float*)d_in[3];  const float* b_e1 = (const float*)d_in[4];
    const float* W_e2 = (const float*)d_in[5];  const float* b_e2 = (const float*)d_in[6];
    const float* W_e3 = (const float*)d_in[7];  const float* b_e3 = (const float*)d_in[8];
    const float* W_d1 = (const float*)d_in[9];  const float* b_d1 = (const float*)d_in[10];
    const float* W_d2 = (const float*)d_in[11]; const float* b_d2 = (const float*)d_in[12];
    const float* W_d3 = (const float*)d_in[13]; const float* b_d3 = (const float*)d_in[14];
    float* out = (float*)d_out;

    float*  A    = (float*)d_ws;                    // n*160 floats
    __half* H16  = (__half*)(A + (size_t)n * 160);  // n*128 halves
    float*  dinv = (float*)(H16 + (size_t)n * 128); // n
    int* rowptr  = (int*)(dinv + n);                // n+1
    int* colid   = rowptr + n + 1;                  // E
    uintptr_t pp = (uintptr_t)(colid + E);
    pp = (pp + 15) & ~(uintptr_t)15;
    unsigned long long* pairs = (unsigned long long*)pp;  // E
    int* bucket_cnt  = (int*)(pairs + E);           // 512
    int* bucket_base = bucket_cnt + 512;            // 512
    int* bucket_fill = bucket_base + 512;           // 512
    uintptr_t wp = (uintptr_t)(bucket_fill + 512);
    wp = (wp + 15) & ~(uintptr_t)15;
    unsigned short* wt = (unsigned short*)wp;
    // swizzled hi/lo fragment buffers per layer (K*OUT*2 halfs each)
    unsigned short* e1w = wt;             unsigned short* e2w = e1w + 160 * 128 * 2;
    unsigned short* e3w = e2w + 128*128*2; unsigned short* d1w = e3w + 128 * 64 * 2;
    unsigned short* d2w = d1w + 96*128*2;  unsigned short* d3w = d2w + 128 * 128 * 2;

    hipMemsetAsync(bucket_cnt, 0, 512 * sizeof(int), stream);

    int nbc = (E + CHUNK - 1) / CHUNK;
    coarse_hist<<<nbc, 256, 0, stream>>>(ei, bucket_cnt, E);
    scan_buckets<<<1, 512, 0, stream>>>(bucket_cnt, bucket_base, bucket_fill);
    coarse_scatter<<<nbc, 256, 0, stream>>>(ei, bucket_fill, pairs, E);
    fine_csr<<<NB, 256, 0, stream>>>(pairs, bucket_base, rowptr, colid, dinv, n);

    wsplit_kernel<<<(160*128 + 255)/256, 256, 0, stream>>>(W_e1, e1w, 160, 128);
    wsplit_kernel<<<(128*128 + 255)/256, 256, 0, stream>>>(W_e2, e2w, 128, 128);
    wsplit_kernel<<<(128*64  + 255)/256, 256, 0, stream>>>(W_e3, e3w, 128, 64);
    wsplit_kernel<<<(96*128  + 255)/256, 256, 0, stream>>>(W_d1, d1w, 96, 128);
    wsplit_kernel<<<(128*128 + 255)/256, 256, 0, stream>>>(W_d2, d2w, 128, 128);
    wsplit_kernel<<<(128*128 + 255)/256, 256, 0, stream>>>(W_d3, d3w, 128, 128);

    concat_kernel<<<(n * 40 + 255) / 256, 256, 0, stream>>>(
        (const float4*)feature, (const float4*)condition, (float4*)A, n);

    const int ntiles = n / 16;          // 6250 exactly
    const int gb = (ntiles + 7) / 8;    // 8 waves per block
    int pb = (n + 3) / 4;

    // encoder
    gemm_mfma<128, 160><<<gb, 512, 0, stream>>>(A, e1w, dinv, H16, ntiles);
    prop_kernel<128, true><<<pb, 256, 0, stream>>>(H16, dinv, rowptr, colid, b_e1, A, 128, n);
    gemm_mfma<128, 128><<<gb, 512, 0, stream>>>(A, e2w, dinv, H16, ntiles);
    prop_kernel<128, true><<<pb, 256, 0, stream>>>(H16, dinv, rowptr, colid, b_e2, A, 128, n);
    gemm_mfma<64, 128><<<gb, 512, 0, stream>>>(A, e3w, dinv, H16, ntiles);
    prop_kernel<64, false><<<pb, 256, 0, stream>>>(H16, dinv, rowptr, colid, b_e3, A, 96, n);
    condcopy_kernel<<<(n * 8 + 255) / 256, 256, 0, stream>>>(
        (const float4*)condition, (float4*)A, n);

    // decoder
    gemm_mfma<128, 96><<<gb, 512, 0, stream>>>(A, d1w, dinv, H16, ntiles);
    prop_kernel<128, true><<<pb, 256, 0, stream>>>(H16, dinv, rowptr, colid, b_d1, A, 128, n);
    gemm_mfma<128, 128><<<gb, 512, 0, stream>>>(A, d2w, dinv, H16, ntiles);
    prop_kernel<128, true><<<pb, 256, 0, stream>>>(H16, dinv, rowptr, colid, b_d2, A, 128, n);
    gemm_mfma<128, 128><<<gb, 512, 0, stream>>>(A, d3w, dinv, H16, ntiles);
    prop_kernel<128, false><<<pb, 256, 0, stream>>>(H16, dinv, rowptr, colid, b_d3, out, 128, n);
}